// Round 1
// baseline (198.726 us; speedup 1.0000x reference)
//
#include <hip/hip_runtime.h>
#include <hip/hip_bf16.h>
#include <math.h>

#define BS 16
#define NH 12
#define SEQ 1024
#define ROWS (NH * SEQ)          // 12288 rows per batch
#define PRUNE_KEEP 0.4f          // 1 - PRUNING_RATIO

// ---------------------------------------------------------------------------
// Kernel 1: partial column-sum reduction of probes over (h, s).
// grid = (nch, BS); block = 256 threads; thread t owns cols [4t, 4t+3].
// Each block sums rows [chunk*rpc, (chunk+1)*rpc) and writes f64 partials.
// ---------------------------------------------------------------------------
__global__ __launch_bounds__(256) void colsum_partial_kernel(
    const float* __restrict__ probes, double* __restrict__ partials,
    int rows_per_chunk, int nch) {
  const int chunk = blockIdx.x;
  const int b = blockIdx.y;
  const int t = threadIdx.x;

  const size_t row0 = (size_t)b * ROWS + (size_t)chunk * rows_per_chunk;
  const float4* src = (const float4*)(probes + row0 * SEQ) + t;

  double a0 = 0.0, a1 = 0.0, a2 = 0.0, a3 = 0.0;
#pragma unroll 4
  for (int r = 0; r < rows_per_chunk; ++r) {
    float4 v = src[(size_t)r * (SEQ / 4)];
    a0 += v.x; a1 += v.y; a2 += v.z; a3 += v.w;
  }

  double* dst = partials + ((size_t)b * nch + chunk) * SEQ + (size_t)t * 4;
  dst[0] = a0; dst[1] = a1; dst[2] = a2; dst[3] = a3;
}

// ---------------------------------------------------------------------------
// Kernel 2: per-batch — finish mean, lengths/sep/k, bitonic rank, emit mask.
// grid = BS blocks of 1024 threads (one thread per column).
// ---------------------------------------------------------------------------
__global__ __launch_bounds__(1024) void prune_kernel(
    const double* __restrict__ partials, const float* __restrict__ mask,
    float* __restrict__ out, int nch) {
  const int b = blockIdx.x;
  const int tid = threadIdx.x;   // 0..1023 == column index

  __shared__ float s_val[SEQ];
  __shared__ int s_idx[SEQ];
  __shared__ float s_red[SEQ];
  __shared__ unsigned char s_keep[SEQ];
  __shared__ int s_sep, s_k;

  // --- finish the mean in f64, cast once to f32 ---
  double acc = 0.0;
  const double* p = partials + ((size_t)b * nch) * SEQ + tid;
  for (int c = 0; c < nch; ++c) acc += p[(size_t)c * SEQ];
  const float score = (float)(acc * (1.0 / (double)ROWS));

  // --- length = sum(mask[b, :]) (exact: 0/1 values) ---
  s_red[tid] = mask[b * SEQ + tid];
  __syncthreads();
  for (int off = SEQ / 2; off > 0; off >>= 1) {
    if (tid < off) s_red[tid] += s_red[tid + off];
    __syncthreads();
  }
  if (tid == 0) {
    const float length = s_red[0];
    s_sep = (int)(length - 1.0f);
    s_k = (int)(length * PRUNE_KEEP);   // length >= 128 -> k >= 51 > 0
  }
  __syncthreads();
  const int sep = s_sep;
  const int k = s_k;

  // --- invalidate cols {0, sep} ---
  const float sc = (tid == 0 || tid == sep) ? -INFINITY : score;
  s_val[tid] = sc;
  s_idx[tid] = tid;
  __syncthreads();

  // --- bitonic sort, ascending under "before" = (val desc, idx asc).
  //     (val, idx) pairs are distinct -> strict total order == stable argsort.
  for (int kk = 2; kk <= SEQ; kk <<= 1) {
    for (int j = kk >> 1; j > 0; j >>= 1) {
      const int ixj = tid ^ j;
      if (ixj > tid) {
        const bool dir_asc = ((tid & kk) == 0);
        const float v0 = s_val[tid], v1 = s_val[ixj];
        const int i0 = s_idx[tid], i1 = s_idx[ixj];
        // before(e0, e1): e0 ranks earlier (higher score, tie -> lower idx)
        const bool before01 = (v0 > v1) || (v0 == v1 && i0 < i1);
        const bool do_swap = dir_asc ? !before01 : before01;
        if (do_swap) {
          s_val[tid] = v1; s_val[ixj] = v0;
          s_idx[tid] = i1; s_idx[ixj] = i0;
        }
      }
      __syncthreads();
    }
  }

  // --- sorted position == rank; scatter keep flags ---
  s_keep[s_idx[tid]] = (tid < k) ? (unsigned char)1 : (unsigned char)0;
  __syncthreads();

  float o;
  if (tid == 0 || tid == sep) {
    o = 1.0f;                               // forced-keep positions
  } else {
    o = s_keep[tid] ? 1.0f : 0.0f;          // -inf cols can never be top-k
  }
  out[b * SEQ + tid] = o;
}

extern "C" void kernel_launch(void* const* d_in, const int* in_sizes, int n_in,
                              void* d_out, int out_size, void* d_ws, size_t ws_size,
                              hipStream_t stream) {
  const float* probes = (const float*)d_in[0];   // (BS, NH, SEQ, SEQ) f32
  const float* mask = (const float*)d_in[1];     // (BS, 1, 1, SEQ)  f32
  float* out = (float*)d_out;                    // (BS, SEQ)        f32
  double* partials = (double*)d_ws;

  // pick the largest chunk count whose f64 partial buffer fits the workspace
  static const int cand[] = {96, 48, 24, 12, 6, 3, 1};
  int nch = 1;
  for (int i = 0; i < 7; ++i) {
    if ((size_t)BS * cand[i] * SEQ * sizeof(double) <= ws_size) { nch = cand[i]; break; }
  }
  const int rpc = ROWS / nch;

  dim3 grid1(nch, BS);
  colsum_partial_kernel<<<grid1, 256, 0, stream>>>(probes, partials, rpc, nch);
  prune_kernel<<<BS, SEQ, 0, stream>>>(partials, mask, out, nch);
}

// Round 2
// 171.407 us; speedup vs baseline: 1.1594x; 1.1594x over previous
//
#include <hip/hip_runtime.h>
#include <hip/hip_bf16.h>
#include <math.h>
#include <stdint.h>

#define BS 16
#define NH 12
#define SEQ 1024
#define ROWS (NH * SEQ)          // 12288 rows per batch
#define KEEP_FRAC 0.4f           // 1 - PRUNING_RATIO

// ---------------------------------------------------------------------------
// Kernel 1: partial column-sum of probes over (h, s) rows.
// grid = (nch, BS); block = 256; thread t owns cols [4t, 4t+3] (float4).
// Each block sums rows [chunk*rpc, (chunk+1)*rpc) into f64 partials.
// ---------------------------------------------------------------------------
__global__ __launch_bounds__(256) void colsum_partial_kernel(
    const float* __restrict__ probes, double* __restrict__ partials,
    int rows_per_chunk, int nch) {
  const int chunk = blockIdx.x;
  const int b = blockIdx.y;
  const int t = threadIdx.x;

  const size_t row0 = (size_t)b * ROWS + (size_t)chunk * rows_per_chunk;
  const float4* src = (const float4*)(probes + row0 * SEQ) + t;

  double a0 = 0.0, a1 = 0.0, a2 = 0.0, a3 = 0.0;
#pragma unroll 8
  for (int r = 0; r < rows_per_chunk; ++r) {
    float4 v = src[(size_t)r * (SEQ / 4)];
    a0 += v.x; a1 += v.y; a2 += v.z; a3 += v.w;
  }

  double* dst = partials + ((size_t)b * nch + chunk) * SEQ + (size_t)t * 4;
  dst[0] = a0; dst[1] = a1; dst[2] = a2; dst[3] = a3;
}

// ---------------------------------------------------------------------------
// Kernel 2a: wide combine of f64 partials -> f32 scores (mean).
// grid = (BS, SEQ/256); block = 256. Fully coalesced (64 lanes x 8B rows).
// ---------------------------------------------------------------------------
__global__ __launch_bounds__(256) void combine_kernel(
    const double* __restrict__ partials, float* __restrict__ scores, int nch) {
  const int b = blockIdx.x;
  const int col = blockIdx.y * 256 + threadIdx.x;
  const double* p = partials + ((size_t)b * nch) * SEQ + col;
  double acc = 0.0;
#pragma unroll 8
  for (int c = 0; c < nch; ++c) acc += p[(size_t)c * SEQ];
  scores[b * SEQ + col] = (float)(acc * (1.0 / (double)ROWS));
}

// ---------------------------------------------------------------------------
// Kernel 2b: per-batch rank + mask emit. One 1024-thread block per batch.
// Packed u64 keys; bitonic sort with shfl_xor for j<64 (no LDS/barrier),
// LDS only for the 10 phases with j>=64.
// ---------------------------------------------------------------------------
__global__ __launch_bounds__(1024) void rank_kernel(
    const float* __restrict__ scores, const float* __restrict__ mask,
    float* __restrict__ out) {
  const int b = blockIdx.x;
  const int tid = threadIdx.x;        // == column index
  const int lane = tid & 63;
  const int wave = tid >> 6;

  __shared__ unsigned long long s_key[SEQ];
  __shared__ int s_wred[16];
  __shared__ unsigned char s_keep[SEQ];
  __shared__ int s_len;

  // --- length = sum(mask[b,:]) via wave shuffle reduce (mask is exact 0/1) ---
  int mv = (mask[b * SEQ + tid] != 0.0f) ? 1 : 0;
#pragma unroll
  for (int o = 32; o > 0; o >>= 1) mv += __shfl_xor(mv, o);
  if (lane == 0) s_wred[wave] = mv;
  __syncthreads();
  if (tid == 0) {
    int L = 0;
#pragma unroll
    for (int w = 0; w < 16; ++w) L += s_wred[w];
    s_len = L;
  }
  __syncthreads();
  const int len = s_len;
  const int sep = len - 1;                       // len >= 128 -> sep >= 127
  const int k = (int)((float)len * KEEP_FRAC);   // matches f32 reference math

  // --- build distinct sort key: ascending key == (score desc, idx asc) ---
  const float sc = scores[b * SEQ + tid];
  uint32_t u = __float_as_uint(sc);    // scores are positive -> bits monotonic
  if (tid == 0 || tid == sep) u = 0u;  // invalid -> sorts last
  unsigned long long key =
      ((unsigned long long)(u ^ 0xFFFFFFFFu) << 10) | (unsigned)tid;

  // --- bitonic sort (ascending). j<64 phases are in-wave via shfl_xor. ---
  for (int kk = 2; kk <= SEQ; kk <<= 1) {
    for (int j = kk >> 1; j > 0; j >>= 1) {
      unsigned long long pk;
      if (j >= 64) {
        s_key[tid] = key;
        __syncthreads();
        pk = s_key[tid ^ j];
        __syncthreads();
      } else {
        pk = (unsigned long long)__shfl_xor((long long)key, j);
      }
      const bool lower = (tid & j) == 0;
      const bool dir_asc = (tid & kk) == 0;
      const bool keep_min = (dir_asc == lower);
      const bool pk_smaller = pk < key;
      key = (keep_min == pk_smaller) ? pk : key;   // distinct keys -> exact
    }
  }

  // --- sorted position == rank; scatter keep flags; emit ---
  s_keep[(int)(key & 1023ull)] = (tid < k) ? (unsigned char)1 : (unsigned char)0;
  __syncthreads();

  float o;
  if (tid == 0 || tid == sep) o = 1.0f;          // forced keep
  else o = s_keep[tid] ? 1.0f : 0.0f;            // invalid cols never top-k
  out[b * SEQ + tid] = o;
}

extern "C" void kernel_launch(void* const* d_in, const int* in_sizes, int n_in,
                              void* d_out, int out_size, void* d_ws, size_t ws_size,
                              hipStream_t stream) {
  const float* probes = (const float*)d_in[0];   // (BS, NH, SEQ, SEQ) f32
  const float* mask = (const float*)d_in[1];     // (BS, 1, 1, SEQ)  f32
  float* out = (float*)d_out;                    // (BS, SEQ)        f32

  // workspace: [ f64 partials (BS*nch*SEQ) | f32 scores (BS*SEQ) ]
  static const int cand[] = {96, 48, 24, 12, 6, 3, 1};
  int nch = 1;
  for (int i = 0; i < 7; ++i) {
    size_t need = (size_t)BS * cand[i] * SEQ * sizeof(double)
                + (size_t)BS * SEQ * sizeof(float);
    if (need <= ws_size) { nch = cand[i]; break; }
  }
  const int rpc = ROWS / nch;

  double* partials = (double*)d_ws;
  float* d_scores = (float*)((char*)d_ws + (size_t)BS * nch * SEQ * sizeof(double));

  dim3 grid1(nch, BS);
  colsum_partial_kernel<<<grid1, 256, 0, stream>>>(probes, partials, rpc, nch);

  dim3 grid2(BS, SEQ / 256);
  combine_kernel<<<grid2, 256, 0, stream>>>(partials, d_scores, nch);

  rank_kernel<<<BS, SEQ, 0, stream>>>(d_scores, mask, out);
}

// Round 3
// 147.460 us; speedup vs baseline: 1.3477x; 1.1624x over previous
//
#include <hip/hip_runtime.h>
#include <hip/hip_bf16.h>
#include <math.h>
#include <stdint.h>

#define BS 16
#define NH 12
#define SEQ 1024
#define ROWS (NH * SEQ)          // 12288 rows per batch
#define KEEP_FRAC 0.4f           // 1 - PRUNING_RATIO

typedef float f32x4 __attribute__((ext_vector_type(4)));

// ---------------------------------------------------------------------------
// Kernel 1: partial column-sum of probes over (h, s) rows.
// grid = (nch, BS); block = 256; thread t owns cols [4t, 4t+3] (16B loads).
// nch=128 -> 2048 blocks = exactly 8 blocks/CU -> 32/32 waves occupancy.
// f64 accumulate in-kernel, single rounding to f32 partial on store.
// Nontemporal loads: 805 MB is streamed exactly once.
// ---------------------------------------------------------------------------
__global__ __launch_bounds__(256, 8) void colsum_partial_kernel(
    const float* __restrict__ probes, float* __restrict__ partials,
    int rows_per_chunk, int nch) {
  const int chunk = blockIdx.x;
  const int b = blockIdx.y;
  const int t = threadIdx.x;

  const size_t row0 = (size_t)b * ROWS + (size_t)chunk * rows_per_chunk;
  const f32x4* src = (const f32x4*)(probes + row0 * SEQ) + t;

  double a0 = 0.0, a1 = 0.0, a2 = 0.0, a3 = 0.0;
#pragma unroll 8
  for (int r = 0; r < rows_per_chunk; ++r) {
    f32x4 v = __builtin_nontemporal_load(src + (size_t)r * (SEQ / 4));
    a0 += v.x; a1 += v.y; a2 += v.z; a3 += v.w;
  }

  f32x4 o; o.x = (float)a0; o.y = (float)a1; o.z = (float)a2; o.w = (float)a3;
  *(f32x4*)(partials + ((size_t)b * nch + chunk) * SEQ + (size_t)t * 4) = o;
}

// ---------------------------------------------------------------------------
// Kernel 2 (fused combine + rank): one 1024-thread block per batch.
// Combine f32 partials in f64 -> score; length/sep/k; packed-u64 bitonic
// rank (shfl_xor for j<64, LDS only for j>=64); emit mask.
// ---------------------------------------------------------------------------
__global__ __launch_bounds__(1024) void rank_kernel(
    const float* __restrict__ partials, const float* __restrict__ mask,
    float* __restrict__ out, int nch) {
  const int b = blockIdx.x;
  const int tid = threadIdx.x;        // == column index
  const int lane = tid & 63;
  const int wave = tid >> 6;

  __shared__ unsigned long long s_key[SEQ];
  __shared__ int s_wred[16];
  __shared__ unsigned char s_keep[SEQ];
  __shared__ int s_len;

  // --- combine partials (coalesced: consecutive tid -> consecutive addr) ---
  double acc = 0.0;
  const float* p = partials + (size_t)b * nch * SEQ + tid;
#pragma unroll 8
  for (int c = 0; c < nch; ++c) acc += (double)p[(size_t)c * SEQ];
  const float score = (float)(acc * (1.0 / (double)ROWS));

  // --- length = sum(mask[b,:]) via wave shuffle reduce (mask is exact 0/1) ---
  int mv = (mask[b * SEQ + tid] != 0.0f) ? 1 : 0;
#pragma unroll
  for (int o = 32; o > 0; o >>= 1) mv += __shfl_xor(mv, o);
  if (lane == 0) s_wred[wave] = mv;
  __syncthreads();
  if (tid == 0) {
    int L = 0;
#pragma unroll
    for (int w = 0; w < 16; ++w) L += s_wred[w];
    s_len = L;
  }
  __syncthreads();
  const int len = s_len;
  const int sep = len - 1;                       // len >= 128 -> sep >= 127
  const int k = (int)((float)len * KEEP_FRAC);   // bit-matches f32 ref math

  // --- build distinct sort key: ascending key == (score desc, idx asc) ---
  uint32_t u = __float_as_uint(score); // scores positive -> bits monotonic
  if (tid == 0 || tid == sep) u = 0u;  // invalid -> sorts last
  unsigned long long key =
      ((unsigned long long)(u ^ 0xFFFFFFFFu) << 10) | (unsigned)tid;

  // --- bitonic sort (ascending). j<64 phases in-wave via shfl_xor. ---
  for (int kk = 2; kk <= SEQ; kk <<= 1) {
    for (int j = kk >> 1; j > 0; j >>= 1) {
      unsigned long long pk;
      if (j >= 64) {
        s_key[tid] = key;
        __syncthreads();
        pk = s_key[tid ^ j];
        __syncthreads();
      } else {
        pk = (unsigned long long)__shfl_xor((long long)key, j);
      }
      const bool lower = (tid & j) == 0;
      const bool dir_asc = (tid & kk) == 0;
      const bool keep_min = (dir_asc == lower);
      const bool pk_smaller = pk < key;
      key = (keep_min == pk_smaller) ? pk : key;   // distinct keys -> exact
    }
  }

  // --- sorted position == rank; scatter keep flags; emit ---
  s_keep[(int)(key & 1023ull)] = (tid < k) ? (unsigned char)1 : (unsigned char)0;
  __syncthreads();

  float o;
  if (tid == 0 || tid == sep) o = 1.0f;          // forced keep
  else o = s_keep[tid] ? 1.0f : 0.0f;            // invalid cols never top-k
  out[b * SEQ + tid] = o;
}

extern "C" void kernel_launch(void* const* d_in, const int* in_sizes, int n_in,
                              void* d_out, int out_size, void* d_ws, size_t ws_size,
                              hipStream_t stream) {
  const float* probes = (const float*)d_in[0];   // (BS, NH, SEQ, SEQ) f32
  const float* mask = (const float*)d_in[1];     // (BS, 1, 1, SEQ)  f32
  float* out = (float*)d_out;                    // (BS, SEQ)        f32
  float* partials = (float*)d_ws;

  // pick the largest chunk count (divisor of ROWS) whose f32 partials fit ws
  static const int cand[] = {128, 96, 64, 48, 32, 24, 16, 12, 8, 6, 4, 3, 2, 1};
  int nch = 1;
  for (int i = 0; i < 14; ++i) {
    if ((size_t)BS * cand[i] * SEQ * sizeof(float) <= ws_size) { nch = cand[i]; break; }
  }
  const int rpc = ROWS / nch;

  dim3 grid1(nch, BS);
  colsum_partial_kernel<<<grid1, 256, 0, stream>>>(probes, partials, rpc, nch);
  rank_kernel<<<BS, SEQ, 0, stream>>>(partials, mask, out, nch);
}

// Round 4
// 145.901 us; speedup vs baseline: 1.3621x; 1.0107x over previous
//
#include <hip/hip_runtime.h>
#include <hip/hip_bf16.h>
#include <math.h>
#include <stdint.h>

#define BS 16
#define NH 12
#define SEQ 1024
#define ROWS (NH * SEQ)          // 12288 rows per batch
#define KEEP_FRAC 0.4f           // 1 - PRUNING_RATIO

typedef float f32x4 __attribute__((ext_vector_type(4)));

// ---------------------------------------------------------------------------
// Kernel 1: partial column-sum of probes over (h, s) rows.
// grid = (nch, BS); block = 256; thread t owns cols [4t, 4t+3] (16B loads).
// nch=128 -> 2048 blocks = exactly 8 blocks/CU -> 32/32 waves occupancy.
// f64 accumulate in-kernel, single rounding to f32 partial on store.
// ---------------------------------------------------------------------------
__global__ __launch_bounds__(256, 8) void colsum_partial_kernel(
    const float* __restrict__ probes, float* __restrict__ partials,
    int rows_per_chunk, int nch) {
  const int chunk = blockIdx.x;
  const int b = blockIdx.y;
  const int t = threadIdx.x;

  const size_t row0 = (size_t)b * ROWS + (size_t)chunk * rows_per_chunk;
  const f32x4* src = (const f32x4*)(probes + row0 * SEQ) + t;

  double a0 = 0.0, a1 = 0.0, a2 = 0.0, a3 = 0.0;
#pragma unroll 8
  for (int r = 0; r < rows_per_chunk; ++r) {
    f32x4 v = __builtin_nontemporal_load(src + (size_t)r * (SEQ / 4));
    a0 += v.x; a1 += v.y; a2 += v.z; a3 += v.w;
  }

  f32x4 o; o.x = (float)a0; o.y = (float)a1; o.z = (float)a2; o.w = (float)a3;
  *(f32x4*)(partials + ((size_t)b * nch + chunk) * SEQ + (size_t)t * 4) = o;
}

// ---------------------------------------------------------------------------
// Kernel 2: WIDE combine of f32 partials -> f32 scores (mean).
// grid = (BS, SEQ/64) = 256 blocks x 64 threads: all 256 CUs pull the 8.4 MB
// partial buffer in parallel (~2-3 us) instead of 16 CUs (~15-20 us).
// ---------------------------------------------------------------------------
__global__ __launch_bounds__(64) void combine_kernel(
    const float* __restrict__ partials, float* __restrict__ scores, int nch) {
  const int b = blockIdx.x;
  const int col = blockIdx.y * 64 + threadIdx.x;
  const float* p = partials + (size_t)b * nch * SEQ + col;
  double acc = 0.0;
#pragma unroll 8
  for (int c = 0; c < nch; ++c) acc += (double)p[(size_t)c * SEQ];
  scores[b * SEQ + col] = (float)(acc * (1.0 / (double)ROWS));
}

// ---------------------------------------------------------------------------
// Kernel 3: per-batch rank + mask emit. One 1024-thread block per batch.
// Packed u64 keys; bitonic sort with shfl_xor for j<64 (no LDS/barrier),
// LDS only for the 10 phases with j>=64. Reads only 4 KB of scores/block.
// ---------------------------------------------------------------------------
__global__ __launch_bounds__(1024) void rank_kernel(
    const float* __restrict__ scores, const float* __restrict__ mask,
    float* __restrict__ out) {
  const int b = blockIdx.x;
  const int tid = threadIdx.x;        // == column index
  const int lane = tid & 63;
  const int wave = tid >> 6;

  __shared__ unsigned long long s_key[SEQ];
  __shared__ int s_wred[16];
  __shared__ unsigned char s_keep[SEQ];
  __shared__ int s_len;

  // --- length = sum(mask[b,:]) via wave shuffle reduce (mask is exact 0/1) ---
  int mv = (mask[b * SEQ + tid] != 0.0f) ? 1 : 0;
#pragma unroll
  for (int o = 32; o > 0; o >>= 1) mv += __shfl_xor(mv, o);
  if (lane == 0) s_wred[wave] = mv;
  __syncthreads();
  if (tid == 0) {
    int L = 0;
#pragma unroll
    for (int w = 0; w < 16; ++w) L += s_wred[w];
    s_len = L;
  }
  __syncthreads();
  const int len = s_len;
  const int sep = len - 1;                       // len >= 128 -> sep >= 127
  const int k = (int)((float)len * KEEP_FRAC);   // bit-matches f32 ref math

  // --- build distinct sort key: ascending key == (score desc, idx asc) ---
  const float score = scores[b * SEQ + tid];
  uint32_t u = __float_as_uint(score); // scores positive -> bits monotonic
  if (tid == 0 || tid == sep) u = 0u;  // invalid -> sorts last
  unsigned long long key =
      ((unsigned long long)(u ^ 0xFFFFFFFFu) << 10) | (unsigned)tid;

  // --- bitonic sort (ascending). j<64 phases in-wave via shfl_xor. ---
  for (int kk = 2; kk <= SEQ; kk <<= 1) {
    for (int j = kk >> 1; j > 0; j >>= 1) {
      unsigned long long pk;
      if (j >= 64) {
        s_key[tid] = key;
        __syncthreads();
        pk = s_key[tid ^ j];
        __syncthreads();
      } else {
        pk = (unsigned long long)__shfl_xor((long long)key, j);
      }
      const bool lower = (tid & j) == 0;
      const bool dir_asc = (tid & kk) == 0;
      const bool keep_min = (dir_asc == lower);
      const bool pk_smaller = pk < key;
      key = (keep_min == pk_smaller) ? pk : key;   // distinct keys -> exact
    }
  }

  // --- sorted position == rank; scatter keep flags; emit ---
  s_keep[(int)(key & 1023ull)] = (tid < k) ? (unsigned char)1 : (unsigned char)0;
  __syncthreads();

  float o;
  if (tid == 0 || tid == sep) o = 1.0f;          // forced keep
  else o = s_keep[tid] ? 1.0f : 0.0f;            // invalid cols never top-k
  out[b * SEQ + tid] = o;
}

extern "C" void kernel_launch(void* const* d_in, const int* in_sizes, int n_in,
                              void* d_out, int out_size, void* d_ws, size_t ws_size,
                              hipStream_t stream) {
  const float* probes = (const float*)d_in[0];   // (BS, NH, SEQ, SEQ) f32
  const float* mask = (const float*)d_in[1];     // (BS, 1, 1, SEQ)  f32
  float* out = (float*)d_out;                    // (BS, SEQ)        f32

  // ws layout: [ f32 partials (BS*nch*SEQ) | f32 scores (BS*SEQ) ]
  static const int cand[] = {128, 96, 64, 48, 32, 24, 16, 12, 8, 6, 4, 3, 2, 1};
  int nch = 1;
  for (int i = 0; i < 14; ++i) {
    size_t need = (size_t)BS * cand[i] * SEQ * sizeof(float)
                + (size_t)BS * SEQ * sizeof(float);
    if (need <= ws_size) { nch = cand[i]; break; }
  }
  const int rpc = ROWS / nch;

  float* partials = (float*)d_ws;
  float* d_scores = (float*)((char*)d_ws + (size_t)BS * nch * SEQ * sizeof(float));

  dim3 grid1(nch, BS);
  colsum_partial_kernel<<<grid1, 256, 0, stream>>>(probes, partials, rpc, nch);

  dim3 grid2(BS, SEQ / 64);
  combine_kernel<<<grid2, 64, 0, stream>>>(partials, d_scores, nch);

  rank_kernel<<<BS, SEQ, 0, stream>>>(d_scores, mask, out);
}